// Round 7
// baseline (1699.296 us; speedup 1.0000x reference)
//
#include <hip/hip_runtime.h>
#include <hip/hip_bf16.h>
#include <math.h>

using bf16 = __hip_bfloat16;
typedef short s16x8 __attribute__((ext_vector_type(8)));
typedef float f32x4 __attribute__((ext_vector_type(4)));

#define ROWS 8192   // B*S
#define DH 768

static inline int cdiv(int a, int b) { return (a + b - 1) / b; }

// async global->LDS, 16B per lane; LDS dest must be wave-uniform base + lane*16
__device__ __forceinline__ void gld16(const bf16* g, bf16* l)
{
    __builtin_amdgcn_global_load_lds(
        (const __attribute__((address_space(1))) void*)g,
        (__attribute__((address_space(3))) void*)l, 16, 0, 0);
}

// ---------------------------------------------------------------------------
// Generic bf16 GEMM: C[M,N] = scale * (A[M,K] @ Bt[N,K]^T) + bias[N]
// Double-buffered LDS + global_load_lds prefetch, ONE barrier per K-iter.
// L2 swizzle: supertiles of 8 M-blocks x all N-panels so the ~256 concurrent
// blocks share a small A/B working set (fits aggregate L2).
// ---------------------------------------------------------------------------
__global__ __launch_bounds__(256)
void gemm_bf16_nt(const bf16* __restrict__ A, const bf16* __restrict__ Bt,
                  void* __restrict__ Cout, const float* __restrict__ bias,
                  int K, int lda, int ldb, int ldc,
                  long long aO, long long aI, long long bO, long long bI,
                  long long cO, long long cI, int zInner,
                  float scale, int storeBf16, int nMask)
{
    int z = blockIdx.z;
    int zo = z / zInner, zi = z - zo * zInner;
    const bf16* Ab = A + (long long)zo * aO + (long long)zi * aI;
    const bf16* Bb = Bt + (long long)zo * bO + (long long)zi * bI;
    long long cOff = (long long)zo * cO + (long long)zi * cI;

    __shared__ bf16 As[2 * 128 * 32];
    __shared__ bf16 Bs[2 * 128 * 32];

    int tid = threadIdx.x;
    int lane = tid & 63;
    int wid = tid >> 6;
    int wm = wid >> 1, wn = wid & 1;

    // L2-locality swizzle (identity when gridDim.x % 8 != 0)
    int nx = gridDim.x, ny = gridDim.y;
    int bx, by;
    if ((nx & 7) == 0) {
        int lin = blockIdx.y * nx + blockIdx.x;
        int t = lin >> 3;
        bx = (lin & 7) + (t / ny) * 8;
        by = t - (t / ny) * ny;
    } else { bx = blockIdx.x; by = blockIdx.y; }
    int m0 = bx * 128;
    int n0 = by * 128;

    f32x4 acc[4][4];
    f32x4 zero = {0.f, 0.f, 0.f, 0.f};
#pragma unroll
    for (int i = 0; i < 4; i++)
#pragma unroll
        for (int j = 0; j < 4; j++) acc[i][j] = zero;

    int f0 = tid, f1 = tid + 256;
    int r0 = f0 >> 2, c0 = (f0 & 3) * 8;
    int r1 = f1 >> 2, c1 = (f1 & 3) * 8;
    const bf16* a0p = Ab + (long long)(m0 + r0) * lda + c0;
    const bf16* a1p = Ab + (long long)(m0 + r1) * lda + c1;
    const bf16* b0p = Bb + (long long)(n0 + r0) * ldb + c0;
    const bf16* b1p = Bb + (long long)(n0 + r1) * ldb + c1;

    // wave-uniform LDS staging bases; lane l lands at base + l*8 elems (16B)
    bf16* asw0 = As + wid * 512;
    bf16* asw1 = As + 2048 + wid * 512;
    bf16* bsw0 = Bs + wid * 512;
    bf16* bsw1 = Bs + 2048 + wid * 512;

    int mrow = lane & 15;
    int kcol = (lane >> 4) * 8;
    const bf16* aRead = As + (wm * 64 + mrow) * 32 + kcol;
    const bf16* bRead = Bs + (wn * 64 + mrow) * 32 + kcol;

    int nIter = K >> 5;
    // prologue: tile 0 -> buf 0
    gld16(a0p, asw0);
    gld16(a1p, asw1);
    gld16(b0p, bsw0);
    gld16(b1p, bsw1);

    for (int it = 0; it < nIter; it++) {
        __syncthreads();   // drains tile-it loads; also fences buf reuse
        int cur = (it & 1) * 4096;
        int nxt = 4096 - cur;
        if (it + 1 < nIter) {
            int kn = (it + 1) << 5;
            gld16(a0p + kn, asw0 + nxt);
            gld16(a1p + kn, asw1 + nxt);
            gld16(b0p + kn, bsw0 + nxt);
            gld16(b1p + kn, bsw1 + nxt);
        }
        s16x8 af[4], bfr[4];
#pragma unroll
        for (int i = 0; i < 4; i++) af[i] = *(const s16x8*)(aRead + cur + i * 16 * 32);
#pragma unroll
        for (int i = 0; i < 4; i++) bfr[i] = *(const s16x8*)(bRead + cur + i * 16 * 32);
#pragma unroll
        for (int mi = 0; mi < 4; mi++)
#pragma unroll
            for (int ni = 0; ni < 4; ni++)
                acc[mi][ni] = __builtin_amdgcn_mfma_f32_16x16x32_bf16(
                    af[mi], bfr[ni], acc[mi][ni], 0, 0, 0);
    }

    int colL = lane & 15;
    int rq = (lane >> 4) * 4;
#pragma unroll
    for (int ni = 0; ni < 4; ni++) {
        int col = n0 + wn * 64 + ni * 16 + colL;
        if (col >= nMask) continue;
        float bv = bias ? bias[col] : 0.f;
#pragma unroll
        for (int mi = 0; mi < 4; mi++) {
#pragma unroll
            for (int r = 0; r < 4; r++) {
                int row = m0 + wm * 64 + mi * 16 + rq + r;
                float v = acc[mi][ni][r] * scale + bv;
                long long ci = cOff + (long long)row * ldc + col;
                if (storeBf16) ((bf16*)Cout)[ci] = __float2bfloat16(v);
                else           ((float*)Cout)[ci] = v;
            }
        }
    }
}

// ---------------------------------------------------------------------------
// Weight transpose+cast: in [z][K][N] fp32 -> out [z][N][K] bf16
// ---------------------------------------------------------------------------
__global__ __launch_bounds__(256)
void transpose_cast(const float* __restrict__ in, bf16* __restrict__ out, int K, int N)
{
    long long zoff = (long long)blockIdx.z * K * N;
    int k0 = blockIdx.x * 32, n0 = blockIdx.y * 32;
    __shared__ float t[32][33];
    int tx = threadIdx.x & 31, ty = threadIdx.x >> 5;  // ty: 0..7
#pragma unroll
    for (int j = 0; j < 32; j += 8)
        t[ty + j][tx] = in[zoff + (long long)(k0 + ty + j) * N + n0 + tx];
    __syncthreads();
#pragma unroll
    for (int j = 0; j < 32; j += 8)
        out[zoff + (long long)(n0 + ty + j) * K + k0 + tx] = __float2bfloat16(t[tx][ty + j]);
}

// ---------------------------------------------------------------------------
// zero-fill u64 buffer (must run every call; harness poisons ws with 0xAA)
// ---------------------------------------------------------------------------
__global__ void zero_u64(unsigned long long* __restrict__ p, int n)
{
    int i = blockIdx.x * 256 + threadIdx.x;
    if (i < n) p[i] = 0ull;
}

// ---------------------------------------------------------------------------
// prep_x: h=x (fp32), hb=bf16(x), xc = [h1|h1|h2|h1] per row (width 3072).
// A-side reads offset 0 (blocks h1,h1,h2), B-side reads offset 768
// (blocks h1,h2,h1): A.B^T = h1h1 + h1h2 + h2h1 — near-fp32-accurate x.x^T.
// ---------------------------------------------------------------------------
__global__ __launch_bounds__(256)
void prep_x(const float* __restrict__ x, float* __restrict__ h,
            bf16* __restrict__ hb, bf16* __restrict__ xc)
{
    int i = blockIdx.x * 256 + threadIdx.x;
    if (i >= ROWS * DH) return;
    float v = x[i];
    h[i] = v;
    bf16 h1 = __float2bfloat16(v);
    float r1 = v - __bfloat162float(h1);
    bf16 h2 = __float2bfloat16(r1);
    hb[i] = h1;
    int row = i / DH, d = i - row * DH;
    long long xb = (long long)row * 3072;
    xc[xb + d] = h1;
    xc[xb + 768 + d] = h1;
    xc[xb + 1536 + d] = h2;
    xc[xb + 2304 + d] = h1;
}

// ---------------------------------------------------------------------------
// Fused top-k: register-resident wave-local top-8 (no barriers in the scan),
// wave-0 merge of 4x8 candidates, then exact fp64 rerank -> top-5 ->
// symmetric adjacency bits (+ self loop). Candidate set identical to the
// previous block-scan version (per-wave top-8 covers disjoint index ranges).
// ---------------------------------------------------------------------------
__global__ __launch_bounds__(256)
void topk_rerank(const float* __restrict__ sim, const float* __restrict__ x,
                 unsigned long long* __restrict__ mask)
{
    int row = blockIdx.x;            // b*1024 + s
    int b = row >> 10, s = row & 1023;
    int tid = threadIdx.x;
    int wid = tid >> 6, lane = tid & 63;

    __shared__ float wvals[4][8];
    __shared__ int   widx[4][8];
    __shared__ int   cand[8];
    __shared__ double val[8];

    // lane's 4 contiguous sim elements: indices base..base+3
    int base = wid * 256 + lane * 4;
    float4 vv = *(const float4*)(sim + (long long)row * 1024 + base);
    float v0 = vv.x, v1 = vv.y, v2 = vv.z, v3 = vv.w;

    for (int r = 0; r < 8; r++) {
        // local max (lowest index wins ties)
        float bv = v0; int bi = base;
        if (v1 > bv) { bv = v1; bi = base + 1; }
        if (v2 > bv) { bv = v2; bi = base + 2; }
        if (v3 > bv) { bv = v3; bi = base + 3; }
        // 64-lane wave reduce, wave-synchronous
#pragma unroll
        for (int o = 1; o < 64; o <<= 1) {
            float ov = __shfl_xor(bv, o);
            int   oi = __shfl_xor(bi, o);
            if (ov > bv || (ov == bv && oi < bi)) { bv = ov; bi = oi; }
        }
        // owning lane invalidates its register slot
        if ((bi >> 2) == (wid * 64 + lane)) {
            int sl = bi & 3;
            if (sl == 0) v0 = -3.4e38f;
            else if (sl == 1) v1 = -3.4e38f;
            else if (sl == 2) v2 = -3.4e38f;
            else v3 = -3.4e38f;
        }
        if (lane == 0) { wvals[wid][r] = bv; widx[wid][r] = bi; }
    }
    __syncthreads();
    // wave 0 merges 32 candidates -> global top-8
    if (wid == 0) {
        float mv = -3.4e38f; int mi = 0x7fffffff;
        if (lane < 32) { mv = wvals[lane >> 3][lane & 7]; mi = widx[lane >> 3][lane & 7]; }
        for (int r = 0; r < 8; r++) {
            float bv = mv; int bi = mi;
#pragma unroll
            for (int o = 1; o < 32; o <<= 1) {
                float ov = __shfl_xor(bv, o, 32);
                int   oi = __shfl_xor(bi, o, 32);
                if (ov > bv || (ov == bv && oi < bi)) { bv = ov; bi = oi; }
            }
            if (lane < 32 && bi == mi) mv = -3.4e38f;  // invalidate winner owner
            if (lane == 0) cand[r] = bi;
        }
    }
    __syncthreads();
    // fp64 exact rerank: group g (32 lanes) handles candidate g, float4 loads
    int g = tid >> 5, t = tid & 31;
    int c = cand[g];
    const float4* xs4 = (const float4*)(x + (long long)row * DH);
    const float4* xc4 = (const float4*)(x + ((long long)b * 1024 + c) * DH);
    double acc = 0.0;
#pragma unroll
    for (int j = 0; j < 6; j++) {
        float4 a = xs4[t + j * 32];
        float4 q = xc4[t + j * 32];
        acc += (double)a.x * q.x + (double)a.y * q.y
             + (double)a.z * q.z + (double)a.w * q.w;
    }
#pragma unroll
    for (int o = 16; o; o >>= 1) acc += __shfl_xor(acc, o, 32);
    if (t == 0) val[g] = acc;
    __syncthreads();
    if (tid == 0) {
        bool used[8] = {false, false, false, false, false, false, false, false};
        for (int r = 0; r < 5; r++) {
            int best = -1;
            for (int j = 0; j < 8; j++) {
                if (used[j]) continue;
                if (best < 0 || val[j] > val[best] ||
                    (val[j] == val[best] && cand[j] < cand[best])) best = j;
            }
            used[best] = true;
            int ci = cand[best];
            atomicOr(&mask[((long long)b * 1024 + s) * 16 + (ci >> 6)], 1ull << (ci & 63));
            atomicOr(&mask[((long long)b * 1024 + ci) * 16 + (s >> 6)], 1ull << (s & 63));
        }
        atomicOr(&mask[(long long)row * 16 + (s >> 6)], 1ull << (s & 63));
    }
}

__global__ void calc_dinv(const unsigned long long* __restrict__ mask,
                          float* __restrict__ dinv, int n)
{
    int i = blockIdx.x * 256 + threadIdx.x;
    if (i >= n) return;
    int c = 0;
#pragma unroll
    for (int w = 0; w < 16; w++) c += __popcll(mask[(long long)i * 16 + w]);
    dinv[i] = 1.f / sqrtf((float)c);
}

// ---------------------------------------------------------------------------
// SpMM: out[b,s,:] = sum_t dinv[s]*dinv[t]*g[b,t,:]  + bias  (bitmask rows)
// ---------------------------------------------------------------------------
__global__ __launch_bounds__(256)
void spmm(const unsigned long long* __restrict__ mask, const float* __restrict__ dinv,
          const float* __restrict__ g, const float* __restrict__ bias,
          float* __restrict__ out)
{
    int s = blockIdx.x, b = blockIdx.y;
    int row = b * 1024 + s;
    __shared__ unsigned long long mrow[16];
    int tid = threadIdx.x;
    if (tid < 16) mrow[tid] = mask[(long long)row * 16 + tid];
    __syncthreads();
    float ds = dinv[row];
    float a0 = 0.f, a1 = 0.f, a2 = 0.f;
    const float* gb = g + (long long)b * 1024 * DH;
    const float* db = dinv + b * 1024;
    for (int w = 0; w < 16; w++) {
        unsigned long long bits = mrow[w];
        while (bits) {
            int t = (w << 6) + __ffsll(bits) - 1;
            bits &= bits - 1;
            float c = ds * db[t];
            const float* gr = gb + (long long)t * DH;
            a0 += c * gr[tid];
            a1 += c * gr[tid + 256];
            a2 += c * gr[tid + 512];
        }
    }
    float* o = out + (long long)row * DH;
    o[tid] = a0 + bias[tid];
    o[tid + 256] = a1 + bias[tid + 256];
    o[tid + 512] = a2 + bias[tid + 512];
}

// ---------------------------------------------------------------------------
// Vt transpose: qkvb V-part [b, t, 1536+h*96+d] -> Vt[b,h,d,t], d padded to 128
// ---------------------------------------------------------------------------
__global__ __launch_bounds__(256)
void vt_transpose(const bf16* __restrict__ qkvb, bf16* __restrict__ Vt)
{
    int bh = blockIdx.y;
    int b = bh >> 3, h = bh & 7;
    int t0 = blockIdx.x * 64;
    __shared__ bf16 tile[64][100];
    int tid = threadIdx.x;
    {
        int t = tid >> 2, c0 = (tid & 3) * 24;
        const bf16* src = qkvb + ((long long)(b * 1024 + t0 + t)) * 2304 + 1536 + h * 96 + c0;
#pragma unroll
        for (int j = 0; j < 24; j++) tile[t][c0 + j] = src[j];
    }
    __syncthreads();
    bf16* dst = Vt + ((long long)bh * 128) * 1024 + t0;
    bf16 zb = __float2bfloat16(0.f);
#pragma unroll
    for (int j = 0; j < 32; j++) {
        int f = tid + j * 256;
        int d = f >> 6, t = f & 63;
        dst[(long long)d * 1024 + t] = (d < 96) ? tile[t][d] : zb;
    }
}

// ---------------------------------------------------------------------------
// Row softmax in-place on bf16 P rows of length 1024
// ---------------------------------------------------------------------------
__global__ __launch_bounds__(256)
void softmax_rows(bf16* __restrict__ P)
{
    long long row = blockIdx.x;
    bf16* pr = P + row * 1024;
    int tid = threadIdx.x;
    __shared__ float red[4];
    float v[4];
#pragma unroll
    for (int j = 0; j < 4; j++) v[j] = __bfloat162float(pr[tid * 4 + j]);
    float mx = fmaxf(fmaxf(v[0], v[1]), fmaxf(v[2], v[3]));
    for (int o = 32; o; o >>= 1) mx = fmaxf(mx, __shfl_xor(mx, o));
    if ((tid & 63) == 0) red[tid >> 6] = mx;
    __syncthreads();
    mx = fmaxf(fmaxf(red[0], red[1]), fmaxf(red[2], red[3]));
    __syncthreads();
    float e[4], s = 0.f;
#pragma unroll
    for (int j = 0; j < 4; j++) { e[j] = __expf(v[j] - mx); s += e[j]; }
    for (int o = 32; o; o >>= 1) s += __shfl_xor(s, o);
    if ((tid & 63) == 0) red[tid >> 6] = s;
    __syncthreads();
    s = red[0] + red[1] + red[2] + red[3];
    float inv = 1.f / s;
#pragma unroll
    for (int j = 0; j < 4; j++) pr[tid * 4 + j] = __float2bfloat16(e[j] * inv);
}

// ---------------------------------------------------------------------------
// concat + bf16 cast for gate input
// ---------------------------------------------------------------------------
__global__ void concat_cast(const float* __restrict__ gcn_out, const float* __restrict__ attn_out,
                            bf16* __restrict__ gi)
{
    int i = blockIdx.x * 256 + threadIdx.x;
    if (i >= ROWS * DH) return;
    int r = i / DH, d = i - r * DH;
    gi[(long long)r * 1536 + d] = __float2bfloat16(gcn_out[i]);
    gi[(long long)r * 1536 + 768 + d] = __float2bfloat16(attn_out[i]);
}

// ---------------------------------------------------------------------------
// gate sigmoid + fuse + residual + LayerNorm; writes h (fp32) and hb (bf16)
// ---------------------------------------------------------------------------
__global__ __launch_bounds__(256)
void fuse_ln(const float* __restrict__ gate_lin, const float* __restrict__ gcn_out,
             const float* __restrict__ attn_out, float* __restrict__ h, bf16* __restrict__ hb,
             const float* __restrict__ lns, const float* __restrict__ lnb)
{
    int row = blockIdx.x;
    long long base = (long long)row * DH;
    int tid = threadIdx.x;
    __shared__ float red[4];
    float xv[3];
#pragma unroll
    for (int j = 0; j < 3; j++) {
        int d = tid + j * 256;
        float gl = gate_lin[base + d];
        float gv = 1.f / (1.f + __expf(-gl));
        float f = gv * gcn_out[base + d] + (1.f - gv) * attn_out[base + d];
        xv[j] = f + h[base + d];
    }
    float s = xv[0] + xv[1] + xv[2];
    for (int o = 32; o; o >>= 1) s += __shfl_xor(s, o);
    if ((tid & 63) == 0) red[tid >> 6] = s;
    __syncthreads();
    float mu = (red[0] + red[1] + red[2] + red[3]) * (1.f / 768.f);
    __syncthreads();
    float vs = 0.f;
#pragma unroll
    for (int j = 0; j < 3; j++) { float c = xv[j] - mu; vs += c * c; }
    for (int o = 32; o; o >>= 1) vs += __shfl_xor(vs, o);
    if ((tid & 63) == 0) red[tid >> 6] = vs;
    __syncthreads();
    float var = (red[0] + red[1] + red[2] + red[3]) * (1.f / 768.f);
    float rs = 1.f / sqrtf(var + 1e-5f);
#pragma unroll
    for (int j = 0; j < 3; j++) {
        int d = tid + j * 256;
        float y = (xv[j] - mu) * rs * lns[d] + lnb[d];
        h[base + d] = y;
        hb[base + d] = __float2bfloat16(y);
    }
}

// ---------------------------------------------------------------------------
// host-side GEMM wrapper
// ---------------------------------------------------------------------------
static void gemm(hipStream_t st, const bf16* A, const bf16* Bt, void* C, const float* bias,
                 int M, int N, int K, int lda, int ldb, int ldc,
                 long long aO, long long aI, long long bO, long long bI,
                 long long cO, long long cI, int zInner, int Z,
                 float scale, int storeBf16, int nMask)
{
    dim3 g(M / 128, (N + 127) / 128, Z);
    gemm_bf16_nt<<<g, dim3(256), 0, st>>>(A, Bt, C, bias, K, lda, ldb, ldc,
                                          aO, aI, bO, bI, cO, cI, zInner,
                                          scale, storeBf16, nMask);
}

extern "C" void kernel_launch(void* const* d_in, const int* in_sizes, int n_in,
                              void* d_out, int out_size, void* d_ws, size_t ws_size,
                              hipStream_t stream)
{
    (void)in_sizes; (void)n_in; (void)out_size; (void)ws_size;
    const float* x      = (const float*)d_in[0];
    const float* gcn_w  = (const float*)d_in[1];
    const float* gcn_b  = (const float*)d_in[2];
    const float* ain_w  = (const float*)d_in[3];
    const float* ain_b  = (const float*)d_in[4];
    const float* aout_w = (const float*)d_in[5];
    const float* aout_b = (const float*)d_in[6];
    const float* gate_w = (const float*)d_in[7];
    const float* gate_b = (const float*)d_in[8];
    const float* ln_s   = (const float*)d_in[9];
    const float* ln_b   = (const float*)d_in[10];
    const float* proj_w = (const float*)d_in[11];
    const float* proj_b = (const float*)d_in[12];
    float* out = (float*)d_out;

    // --- workspace layout (~216 MB; aliasing verified per-phase liveness) ---
    char* p = (char*)d_ws;
    auto alloc = [&](size_t bytes) {
        char* r = p;
        p += (bytes + 255) & ~(size_t)255;
        return r;
    };
    bf16* gcn_wt  = (bf16*)alloc((size_t)3 * 768 * 768 * 2);
    bf16* ain_wt  = (bf16*)alloc((size_t)3 * 2304 * 768 * 2);
    bf16* aout_wt = (bf16*)alloc((size_t)3 * 768 * 768 * 2);
    bf16* gate_wt = (bf16*)alloc((size_t)3 * 768 * 1536 * 2);
    bf16* proj_wt = (bf16*)alloc((size_t)768 * 768 * 2);
    bf16* hb      = (bf16*)alloc((size_t)ROWS * DH * 2);
    float* h      = (float*)alloc((size_t)ROWS * DH * 4);
    // qkvb region (37.7MB) also hosts gateinb [ROWS][1536] bf16 (dead-QKV phase)
    bf16* qkvb    = (bf16*)alloc((size_t)ROWS * 2304 * 2);
    bf16* gateinb = qkvb;
    // sim region (33.5MB fp32) also hosts: P (2-batch bf16 scores, 33.5MB)
    // and attn_o [ROWS][DH] fp32 (25.2MB, written after P is dead)
    float* sim    = (float*)alloc((size_t)ROWS * 1024 * 4);
    bf16*  P      = (bf16*)sim;
    float* attn_o = sim;
    unsigned long long* mask = (unsigned long long*)alloc((size_t)ROWS * 16 * 8);
    float* dinv   = (float*)alloc((size_t)ROWS * 4);
    // g region (25.2MB) also hosts gate_l (g dead after spmm)
    float* g      = (float*)alloc((size_t)ROWS * DH * 4);
    float* gate_l = g;
    float* gcn_o  = (float*)alloc((size_t)ROWS * DH * 4);
    bf16* Vt      = (bf16*)alloc((size_t)64 * 128 * 1024 * 2);
    bf16* ob      = (bf16*)alloc((size_t)ROWS * DH * 2);
    // xc [ROWS][3072] bf16 (50.33MB) aliases g+gcn_o exactly (both dead
    // until layer loop; xc dead after the sim GEMM)
    bf16* xc      = (bf16*)g;

    // --- weights -> bf16, transposed [N][K] ---
    transpose_cast<<<dim3(24, 24, 3), 256, 0, stream>>>(gcn_w, gcn_wt, 768, 768);
    transpose_cast<<<dim3(24, 72, 3), 256, 0, stream>>>(ain_w, ain_wt, 768, 2304);
    transpose_cast<<<dim3(24, 24, 3), 256, 0, stream>>>(aout_w, aout_wt, 768, 768);
    transpose_cast<<<dim3(48, 24, 3), 256, 0, stream>>>(gate_w, gate_wt, 1536, 768);
    transpose_cast<<<dim3(24, 24, 1), 256, 0, stream>>>(proj_w, proj_wt, 768, 768);

    // --- x prep ---
    prep_x<<<cdiv(ROWS * DH, 256), 256, 0, stream>>>(x, h, hb, xc);

    // --- sim = x x^T with cross terms: A=[h1,h1,h2] (off 0), B=[h1,h2,h1]
    //     (off 768), K=2304, per batch z ---
    gemm(stream, xc, xc + 768, sim, nullptr, 1024, 1024, 2304, 3072, 3072, 1024,
         (long long)1024 * 3072, 0, (long long)1024 * 3072, 0,
         (long long)1024 * 1024, 0, 1, 8, 1.f, 0, 1024);

    // --- adjacency: fused approx top-8 + exact fp64 rerank -> mask -> dinv ---
    zero_u64<<<cdiv(ROWS * 16, 256), 256, 0, stream>>>(mask, ROWS * 16);
    topk_rerank<<<ROWS, 256, 0, stream>>>(sim, x, mask);
    calc_dinv<<<cdiv(ROWS, 256), 256, 0, stream>>>(mask, dinv, ROWS);

    float sscale = 1.0f / sqrtf(96.0f);

    for (int l = 0; l < 3; l++) {
        // g = h @ gcn_w[l]   (fp32 out, bias added in spmm)
        gemm(stream, hb, gcn_wt + (long long)l * 768 * 768, g, nullptr,
             ROWS, 768, 768, 768, 768, 768, 0, 0, 0, 0, 0, 0, 1, 1, 1.f, 0, 768);
        // gcn_out = A_norm @ g + b
        spmm<<<dim3(1024, 8), 256, 0, stream>>>(mask, dinv, g, gcn_b + l * 768, gcn_o);
        // qkv = h @ w_in + b  (bf16 out)
        gemm(stream, hb, ain_wt + (long long)l * 2304 * 768, qkvb, ain_b + l * 2304,
             ROWS, 2304, 768, 768, 768, 2304, 0, 0, 0, 0, 0, 0, 1, 1, 1.f, 1, 2304);
        // V^T per (b,h), padded to 128 rows
        vt_transpose<<<dim3(16, 64), 256, 0, stream>>>(qkvb, Vt);
        // attention: 2 batches per dispatch (z = local_b*8 + head = 16)
        for (int b0 = 0; b0 < 8; b0 += 2) {
            const bf16* qb = qkvb + (long long)b0 * 1024 * 2304;
            // scores (bf16, scaled): zo=local_b, zi=head
            gemm(stream, qb, qb + 768, P, nullptr, 1024, 1024, 96, 2304, 2304, 1024,
                 (long long)1024 * 2304, 96, (long long)1024 * 2304, 96,
                 (long long)8 * 1024 * 1024, (long long)1024 * 1024, 8, 16,
                 sscale, 1, 1024);
            softmax_rows<<<16384, 256, 0, stream>>>(P);
            // o = P @ V  (bf16 out into ob columns h*96..h*96+95)
            gemm(stream, P, Vt + (long long)b0 * 8 * 128 * 1024,
                 ob + (long long)b0 * 1024 * DH, nullptr,
                 1024, 128, 1024, 1024, 1024, DH,
                 (long long)8 * 1024 * 1024, (long long)1024 * 1024,
                 (long long)8 * 128 * 1024, (long long)128 * 1024,
                 (long long)1024 * DH, 96, 8, 16, 1.f, 1, 96);
        }
        // attn_out = o @ w_out + b  (fp32)   [writes into dead-P region]
        gemm(stream, ob, aout_wt + (long long)l * 768 * 768, attn_o, aout_b + l * 768,
             ROWS, 768, 768, 768, 768, 768, 0, 0, 0, 0, 0, 0, 1, 1, 1.f, 0, 768);
        // gate input concat (bf16)          [writes into dead-QKV region]
        concat_cast<<<cdiv(ROWS * DH, 256), 256, 0, stream>>>(gcn_o, attn_o, gateinb);
        // gate_lin = concat @ gate_w + b  (fp32)  [writes into dead-g region]
        gemm(stream, gateinb, gate_wt + (long long)l * 768 * 1536, gate_l, gate_b + l * 768,
             ROWS, 768, 1536, 1536, 1536, 768, 0, 0, 0, 0, 0, 0, 1, 1, 1.f, 0, 768);
        // sigmoid gate + fuse + residual + LN -> h, hb
        fuse_ln<<<ROWS, 256, 0, stream>>>(gate_l, gcn_o, attn_o, h, hb,
                                          ln_s + l * 768, ln_b + l * 768);
    }

    // out = h @ proj_w + proj_b (fp32)
    gemm(stream, hb, proj_wt, out, proj_b,
         ROWS, 768, 768, 768, 768, 768, 0, 0, 0, 0, 0, 0, 1, 1, 1.f, 0, 768);
}

// Round 8
// 1166.389 us; speedup vs baseline: 1.4569x; 1.4569x over previous
//
#include <hip/hip_runtime.h>
#include <hip/hip_bf16.h>
#include <math.h>

using bf16 = __hip_bfloat16;
typedef short s16x8 __attribute__((ext_vector_type(8)));
typedef float f32x4 __attribute__((ext_vector_type(4)));

#define ROWS 8192   // B*S
#define DH 768

static inline int cdiv(int a, int b) { return (a + b - 1) / b; }

// async global->LDS, 16B per lane; LDS dest must be wave-uniform base + lane*16
__device__ __forceinline__ void gld16(const bf16* g, bf16* l)
{
    __builtin_amdgcn_global_load_lds(
        (const __attribute__((address_space(1))) void*)g,
        (__attribute__((address_space(3))) void*)l, 16, 0, 0);
}

// ---------------------------------------------------------------------------
// Generic bf16 GEMM: C[M,N] = scale * (A[M,K] @ Bt[N,K]^T) + bias[N]
// Double-buffered LDS + global_load_lds prefetch, ONE barrier per K-iter.
// L2 swizzle: supertiles of 8 M-blocks x all N-panels.
// ---------------------------------------------------------------------------
__global__ __launch_bounds__(256)
void gemm_bf16_nt(const bf16* __restrict__ A, const bf16* __restrict__ Bt,
                  void* __restrict__ Cout, const float* __restrict__ bias,
                  int K, int lda, int ldb, int ldc,
                  long long aO, long long aI, long long bO, long long bI,
                  long long cO, long long cI, int zInner,
                  float scale, int storeBf16, int nMask)
{
    int z = blockIdx.z;
    int zo = z / zInner, zi = z - zo * zInner;
    const bf16* Ab = A + (long long)zo * aO + (long long)zi * aI;
    const bf16* Bb = Bt + (long long)zo * bO + (long long)zi * bI;
    long long cOff = (long long)zo * cO + (long long)zi * cI;

    __shared__ bf16 As[2 * 128 * 32];
    __shared__ bf16 Bs[2 * 128 * 32];

    int tid = threadIdx.x;
    int lane = tid & 63;
    int wid = tid >> 6;
    int wm = wid >> 1, wn = wid & 1;

    // L2-locality swizzle (identity when gridDim.x % 8 != 0)
    int nx = gridDim.x, ny = gridDim.y;
    int bx, by;
    if ((nx & 7) == 0) {
        int lin = blockIdx.y * nx + blockIdx.x;
        int t = lin >> 3;
        bx = (lin & 7) + (t / ny) * 8;
        by = t - (t / ny) * ny;
    } else { bx = blockIdx.x; by = blockIdx.y; }
    int m0 = bx * 128;
    int n0 = by * 128;

    f32x4 acc[4][4];
    f32x4 zero = {0.f, 0.f, 0.f, 0.f};
#pragma unroll
    for (int i = 0; i < 4; i++)
#pragma unroll
        for (int j = 0; j < 4; j++) acc[i][j] = zero;

    int f0 = tid, f1 = tid + 256;
    int r0 = f0 >> 2, c0 = (f0 & 3) * 8;
    int r1 = f1 >> 2, c1 = (f1 & 3) * 8;
    const bf16* a0p = Ab + (long long)(m0 + r0) * lda + c0;
    const bf16* a1p = Ab + (long long)(m0 + r1) * lda + c1;
    const bf16* b0p = Bb + (long long)(n0 + r0) * ldb + c0;
    const bf16* b1p = Bb + (long long)(n0 + r1) * ldb + c1;

    bf16* asw0 = As + wid * 512;
    bf16* asw1 = As + 2048 + wid * 512;
    bf16* bsw0 = Bs + wid * 512;
    bf16* bsw1 = Bs + 2048 + wid * 512;

    int mrow = lane & 15;
    int kcol = (lane >> 4) * 8;
    const bf16* aRead = As + (wm * 64 + mrow) * 32 + kcol;
    const bf16* bRead = Bs + (wn * 64 + mrow) * 32 + kcol;

    int nIter = K >> 5;
    gld16(a0p, asw0);
    gld16(a1p, asw1);
    gld16(b0p, bsw0);
    gld16(b1p, bsw1);

    for (int it = 0; it < nIter; it++) {
        __syncthreads();
        int cur = (it & 1) * 4096;
        int nxt = 4096 - cur;
        if (it + 1 < nIter) {
            int kn = (it + 1) << 5;
            gld16(a0p + kn, asw0 + nxt);
            gld16(a1p + kn, asw1 + nxt);
            gld16(b0p + kn, bsw0 + nxt);
            gld16(b1p + kn, bsw1 + nxt);
        }
        s16x8 af[4], bfr[4];
#pragma unroll
        for (int i = 0; i < 4; i++) af[i] = *(const s16x8*)(aRead + cur + i * 16 * 32);
#pragma unroll
        for (int i = 0; i < 4; i++) bfr[i] = *(const s16x8*)(bRead + cur + i * 16 * 32);
#pragma unroll
        for (int mi = 0; mi < 4; mi++)
#pragma unroll
            for (int ni = 0; ni < 4; ni++)
                acc[mi][ni] = __builtin_amdgcn_mfma_f32_16x16x32_bf16(
                    af[mi], bfr[ni], acc[mi][ni], 0, 0, 0);
    }

    int colL = lane & 15;
    int rq = (lane >> 4) * 4;
#pragma unroll
    for (int ni = 0; ni < 4; ni++) {
        int col = n0 + wn * 64 + ni * 16 + colL;
        if (col >= nMask) continue;
        float bv = bias ? bias[col] : 0.f;
#pragma unroll
        for (int mi = 0; mi < 4; mi++) {
#pragma unroll
            for (int r = 0; r < 4; r++) {
                int row = m0 + wm * 64 + mi * 16 + rq + r;
                float v = acc[mi][ni][r] * scale + bv;
                long long ci = cOff + (long long)row * ldc + col;
                if (storeBf16) ((bf16*)Cout)[ci] = __float2bfloat16(v);
                else           ((float*)Cout)[ci] = v;
            }
        }
    }
}

// ---------------------------------------------------------------------------
// Fused flash attention for one layer: S=QK^T (fp32), online softmax,
// O = P V, one dispatch. Grid (8 q-tiles, 64 bh), 256 threads = 4 waves;
// wave owns 32 Q rows (2 stripes of 16). K-tile staged in LDS (128x96),
// P round-trips per-wave LDS (C-layout -> A-operand layout), V read as
// B-frags directly from Vt[bh][d][t] (L2-hot). O written bf16 to ob.
// ---------------------------------------------------------------------------
__global__ __launch_bounds__(256)
void flash_attn(const bf16* __restrict__ qkvb, const bf16* __restrict__ Vt,
                bf16* __restrict__ ob, float sscale)
{
    int qt = blockIdx.x, bh = blockIdx.y;
    int b = bh >> 3, h = bh & 7;
    int q0 = qt * 128;

    __shared__ bf16 Ks[128 * 96];        // 24.6 KB
    __shared__ bf16 Ps[4 * 32 * 136];    // 34.8 KB, per-wave private (pad 136)

    int tid = threadIdx.x, lane = tid & 63, wid = tid >> 6;
    int quad = lane >> 4, m16 = lane & 15;

    // Q fragments in registers (A-operand: m=lane&15, k=quad*8+j)
    s16x8 qf[2][3];
#pragma unroll
    for (int s = 0; s < 2; s++) {
        int qrow = q0 + wid * 32 + s * 16 + m16;
        const bf16* qp = qkvb + (long long)(b * 1024 + qrow) * 2304 + h * 96 + quad * 8;
#pragma unroll
        for (int kk = 0; kk < 3; kk++)
            qf[s][kk] = *(const s16x8*)(qp + kk * 32);
    }

    f32x4 zero = {0.f, 0.f, 0.f, 0.f};
    f32x4 o_acc[2][6];
#pragma unroll
    for (int s = 0; s < 2; s++)
#pragma unroll
        for (int d = 0; d < 6; d++) o_acc[s][d] = zero;
    f32x4 m_run[2], l_run[2];
#pragma unroll
    for (int s = 0; s < 2; s++) {
        m_run[s] = {-3.0e38f, -3.0e38f, -3.0e38f, -3.0e38f};
        l_run[s] = zero;
    }

    bf16* Pw = Ps + wid * (32 * 136);
    const bf16* Kbase = qkvb + (long long)b * 1024 * 2304 + 768 + h * 96;
    const bf16* Vbase = Vt + (long long)bh * 128 * 1024;

    for (int kt = 0; kt < 8; kt++) {
        __syncthreads();                 // protect Ks from prior readers
        // stage K-tile rows kt*128..+127 (96 elems each) via gld16
#pragma unroll
        for (int i = 0; i < 6; i++) {
            int gby = i * 4096 + wid * 1024 + lane * 16;   // byte in tile
            int krow = gby / 192;
            int kcol = (gby - krow * 192) >> 1;
            gld16(Kbase + (long long)(kt * 128 + krow) * 2304 + kcol,
                  Ks + i * 2048 + wid * 512);
        }
        __syncthreads();                 // staging complete (vmcnt drain)

        // S = Q K^T, fp32 acc
        f32x4 sacc[2][8];
#pragma unroll
        for (int s = 0; s < 2; s++)
#pragma unroll
            for (int j = 0; j < 8; j++) sacc[s][j] = zero;
#pragma unroll
        for (int j = 0; j < 8; j++) {
            s16x8 kf[3];
#pragma unroll
            for (int kk = 0; kk < 3; kk++)
                kf[kk] = *(const s16x8*)(Ks + (j * 16 + m16) * 96 + kk * 32 + quad * 8);
#pragma unroll
            for (int s = 0; s < 2; s++)
#pragma unroll
                for (int kk = 0; kk < 3; kk++)
                    sacc[s][j] = __builtin_amdgcn_mfma_f32_16x16x32_bf16(
                        qf[s][kk], kf[kk], sacc[s][j], 0, 0, 0);
        }

        // online softmax per stripe; P -> bf16 -> per-wave LDS
#pragma unroll
        for (int s = 0; s < 2; s++) {
#pragma unroll
            for (int j = 0; j < 8; j++)
#pragma unroll
                for (int c = 0; c < 4; c++) sacc[s][j][c] *= sscale;
            f32x4 tmax = sacc[s][0];
#pragma unroll
            for (int j = 1; j < 8; j++)
#pragma unroll
                for (int c = 0; c < 4; c++) tmax[c] = fmaxf(tmax[c], sacc[s][j][c]);
#pragma unroll
            for (int o = 1; o < 16; o <<= 1)
#pragma unroll
                for (int c = 0; c < 4; c++)
                    tmax[c] = fmaxf(tmax[c], __shfl_xor(tmax[c], o));
            f32x4 mnew, alpha;
#pragma unroll
            for (int c = 0; c < 4; c++) {
                mnew[c] = fmaxf(m_run[s][c], tmax[c]);
                alpha[c] = __expf(m_run[s][c] - mnew[c]);
            }
            f32x4 tsum = zero;
#pragma unroll
            for (int j = 0; j < 8; j++) {
#pragma unroll
                for (int c = 0; c < 4; c++) {
                    float pv = __expf(sacc[s][j][c] - mnew[c]);
                    tsum[c] += pv;
                    Pw[(s * 16 + quad * 4 + c) * 136 + j * 16 + m16] = __float2bfloat16(pv);
                }
            }
#pragma unroll
            for (int o = 1; o < 16; o <<= 1)
#pragma unroll
                for (int c = 0; c < 4; c++) tsum[c] += __shfl_xor(tsum[c], o);
#pragma unroll
            for (int c = 0; c < 4; c++)
                l_run[s][c] = l_run[s][c] * alpha[c] + tsum[c];
            m_run[s] = mnew;
#pragma unroll
            for (int d = 0; d < 6; d++)
#pragma unroll
                for (int c = 0; c < 4; c++) o_acc[s][d][c] *= alpha[c];
        }

        // P A-frags from per-wave LDS (no barrier: wave-private region)
        s16x8 pf[2][4];
#pragma unroll
        for (int s = 0; s < 2; s++)
#pragma unroll
            for (int kk = 0; kk < 4; kk++)
                pf[s][kk] = *(const s16x8*)(Pw + (s * 16 + m16) * 136 + kk * 32 + quad * 8);
        // O += P V  (V B-frags direct from Vt: n=d, k along t)
#pragma unroll
        for (int dt = 0; dt < 6; dt++) {
            s16x8 vf[4];
#pragma unroll
            for (int kk = 0; kk < 4; kk++)
                vf[kk] = *(const s16x8*)(Vbase + (long long)(dt * 16 + m16) * 1024
                                         + kt * 128 + kk * 32 + quad * 8);
#pragma unroll
            for (int s = 0; s < 2; s++)
#pragma unroll
                for (int kk = 0; kk < 4; kk++)
                    o_acc[s][dt] = __builtin_amdgcn_mfma_f32_16x16x32_bf16(
                        pf[s][kk], vf[kk], o_acc[s][dt], 0, 0, 0);
        }
    }

    // epilogue: O /= l, store bf16 into ob[row][h*96+d]
#pragma unroll
    for (int s = 0; s < 2; s++) {
        f32x4 inv;
#pragma unroll
        for (int c = 0; c < 4; c++) inv[c] = 1.f / l_run[s][c];
#pragma unroll
        for (int dt = 0; dt < 6; dt++) {
#pragma unroll
            for (int c = 0; c < 4; c++) {
                int row = q0 + wid * 32 + s * 16 + quad * 4 + c;
                int col = h * 96 + dt * 16 + m16;
                ob[(long long)(b * 1024 + row) * 768 + col] =
                    __float2bfloat16(o_acc[s][dt][c] * inv[c]);
            }
        }
    }
}

// ---------------------------------------------------------------------------
// Weight transpose+cast: in [z][K][N] fp32 -> out [z][N][K] bf16
// ---------------------------------------------------------------------------
__global__ __launch_bounds__(256)
void transpose_cast(const float* __restrict__ in, bf16* __restrict__ out, int K, int N)
{
    long long zoff = (long long)blockIdx.z * K * N;
    int k0 = blockIdx.x * 32, n0 = blockIdx.y * 32;
    __shared__ float t[32][33];
    int tx = threadIdx.x & 31, ty = threadIdx.x >> 5;  // ty: 0..7
#pragma unroll
    for (int j = 0; j < 32; j += 8)
        t[ty + j][tx] = in[zoff + (long long)(k0 + ty + j) * N + n0 + tx];
    __syncthreads();
#pragma unroll
    for (int j = 0; j < 32; j += 8)
        out[zoff + (long long)(n0 + ty + j) * K + k0 + tx] = __float2bfloat16(t[tx][ty + j]);
}

// ---------------------------------------------------------------------------
// zero-fill u64 buffer (must run every call; harness poisons ws with 0xAA)
// ---------------------------------------------------------------------------
__global__ void zero_u64(unsigned long long* __restrict__ p, int n)
{
    int i = blockIdx.x * 256 + threadIdx.x;
    if (i < n) p[i] = 0ull;
}

// ---------------------------------------------------------------------------
// prep_x: h=x (fp32), hb=bf16(x), xc = [h1|h1|h2|h1] per row (width 3072).
// ---------------------------------------------------------------------------
__global__ __launch_bounds__(256)
void prep_x(const float* __restrict__ x, float* __restrict__ h,
            bf16* __restrict__ hb, bf16* __restrict__ xc)
{
    int i = blockIdx.x * 256 + threadIdx.x;
    if (i >= ROWS * DH) return;
    float v = x[i];
    h[i] = v;
    bf16 h1 = __float2bfloat16(v);
    float r1 = v - __bfloat162float(h1);
    bf16 h2 = __float2bfloat16(r1);
    hb[i] = h1;
    int row = i / DH, d = i - row * DH;
    long long xb = (long long)row * 3072;
    xc[xb + d] = h1;
    xc[xb + 768 + d] = h1;
    xc[xb + 1536 + d] = h2;
    xc[xb + 2304 + d] = h1;
}

// ---------------------------------------------------------------------------
// Fused top-k: register-resident wave-local top-8, wave-0 merge, exact fp64
// rerank -> top-5 -> symmetric adjacency bits (+ self loop).
// ---------------------------------------------------------------------------
__global__ __launch_bounds__(256)
void topk_rerank(const float* __restrict__ sim, const float* __restrict__ x,
                 unsigned long long* __restrict__ mask)
{
    int row = blockIdx.x;            // b*1024 + s
    int b = row >> 10, s = row & 1023;
    int tid = threadIdx.x;
    int wid = tid >> 6, lane = tid & 63;

    __shared__ float wvals[4][8];
    __shared__ int   widx[4][8];
    __shared__ int   cand[8];
    __shared__ double val[8];

    int base = wid * 256 + lane * 4;
    float4 vv = *(const float4*)(sim + (long long)row * 1024 + base);
    float v0 = vv.x, v1 = vv.y, v2 = vv.z, v3 = vv.w;

    for (int r = 0; r < 8; r++) {
        float bv = v0; int bi = base;
        if (v1 > bv) { bv = v1; bi = base + 1; }
        if (v2 > bv) { bv = v2; bi = base + 2; }
        if (v3 > bv) { bv = v3; bi = base + 3; }
#pragma unroll
        for (int o = 1; o < 64; o <<= 1) {
            float ov = __shfl_xor(bv, o);
            int   oi = __shfl_xor(bi, o);
            if (ov > bv || (ov == bv && oi < bi)) { bv = ov; bi = oi; }
        }
        if ((bi >> 2) == (wid * 64 + lane)) {
            int sl = bi & 3;
            if (sl == 0) v0 = -3.4e38f;
            else if (sl == 1) v1 = -3.4e38f;
            else if (sl == 2) v2 = -3.4e38f;
            else v3 = -3.4e38f;
        }
        if (lane == 0) { wvals[wid][r] = bv; widx[wid][r] = bi; }
    }
    __syncthreads();
    if (wid == 0) {
        float mv = -3.4e38f; int mi = 0x7fffffff;
        if (lane < 32) { mv = wvals[lane >> 3][lane & 7]; mi = widx[lane >> 3][lane & 7]; }
        for (int r = 0; r < 8; r++) {
            float bv = mv; int bi = mi;
#pragma unroll
            for (int o = 1; o < 32; o <<= 1) {
                float ov = __shfl_xor(bv, o, 32);
                int   oi = __shfl_xor(bi, o, 32);
                if (ov > bv || (ov == bv && oi < bi)) { bv = ov; bi = oi; }
            }
            if (lane < 32 && bi == mi) mv = -3.4e38f;
            if (lane == 0) cand[r] = bi;
        }
    }
    __syncthreads();
    int g = tid >> 5, t = tid & 31;
    int c = cand[g];
    const float4* xs4 = (const float4*)(x + (long long)row * DH);
    const float4* xc4 = (const float4*)(x + ((long long)b * 1024 + c) * DH);
    double acc = 0.0;
#pragma unroll
    for (int j = 0; j < 6; j++) {
        float4 a = xs4[t + j * 32];
        float4 q = xc4[t + j * 32];
        acc += (double)a.x * q.x + (double)a.y * q.y
             + (double)a.z * q.z + (double)a.w * q.w;
    }
#pragma unroll
    for (int o = 16; o; o >>= 1) acc += __shfl_xor(acc, o, 32);
    if (t == 0) val[g] = acc;
    __syncthreads();
    if (tid == 0) {
        bool used[8] = {false, false, false, false, false, false, false, false};
        for (int r = 0; r < 5; r++) {
            int best = -1;
            for (int j = 0; j < 8; j++) {
                if (used[j]) continue;
                if (best < 0 || val[j] > val[best] ||
                    (val[j] == val[best] && cand[j] < cand[best])) best = j;
            }
            used[best] = true;
            int ci = cand[best];
            atomicOr(&mask[((long long)b * 1024 + s) * 16 + (ci >> 6)], 1ull << (ci & 63));
            atomicOr(&mask[((long long)b * 1024 + ci) * 16 + (s >> 6)], 1ull << (s & 63));
        }
        atomicOr(&mask[(long long)row * 16 + (s >> 6)], 1ull << (s & 63));
    }
}

__global__ void calc_dinv(const unsigned long long* __restrict__ mask,
                          float* __restrict__ dinv, int n)
{
    int i = blockIdx.x * 256 + threadIdx.x;
    if (i >= n) return;
    int c = 0;
#pragma unroll
    for (int w = 0; w < 16; w++) c += __popcll(mask[(long long)i * 16 + w]);
    dinv[i] = 1.f / sqrtf((float)c);
}

// ---------------------------------------------------------------------------
// SpMM: out[b,s,:] = sum_t dinv[s]*dinv[t]*g[b,t,:]  + bias  (bitmask rows)
// ---------------------------------------------------------------------------
__global__ __launch_bounds__(256)
void spmm(const unsigned long long* __restrict__ mask, const float* __restrict__ dinv,
          const float* __restrict__ g, const float* __restrict__ bias,
          float* __restrict__ out)
{
    int s = blockIdx.x, b = blockIdx.y;
    int row = b * 1024 + s;
    __shared__ unsigned long long mrow[16];
    int tid = threadIdx.x;
    if (tid < 16) mrow[tid] = mask[(long long)row * 16 + tid];
    __syncthreads();
    float ds = dinv[row];
    float a0 = 0.f, a1 = 0.f, a2 = 0.f;
    const float* gb = g + (long long)b * 1024 * DH;
    const float* db = dinv + b * 1024;
    for (int w = 0; w < 16; w++) {
        unsigned long long bits = mrow[w];
        while (bits) {
            int t = (w << 6) + __ffsll(bits) - 1;
            bits &= bits - 1;
            float c = ds * db[t];
            const float* gr = gb + (long long)t * DH;
            a0 += c * gr[tid];
            a1 += c * gr[tid + 256];
            a2 += c * gr[tid + 512];
        }
    }
    float* o = out + (long long)row * DH;
    o[tid] = a0 + bias[tid];
    o[tid + 256] = a1 + bias[tid + 256];
    o[tid + 512] = a2 + bias[tid + 512];
}

// ---------------------------------------------------------------------------
// Vt transpose: qkvb V-part [b, t, 1536+h*96+d] -> Vt[b,h,d,t], d padded to 128
// ---------------------------------------------------------------------------
__global__ __launch_bounds__(256)
void vt_transpose(const bf16* __restrict__ qkvb, bf16* __restrict__ Vt)
{
    int bh = blockIdx.y;
    int b = bh >> 3, h = bh & 7;
    int t0 = blockIdx.x * 64;
    __shared__ bf16 tile[64][100];
    int tid = threadIdx.x;
    {
        int t = tid >> 2, c0 = (tid & 3) * 24;
        const bf16* src = qkvb + ((long long)(b * 1024 + t0 + t)) * 2304 + 1536 + h * 96 + c0;
#pragma unroll
        for (int j = 0; j < 24; j++) tile[t][c0 + j] = src[j];
    }
    __syncthreads();
    bf16* dst = Vt + ((long long)bh * 128) * 1024 + t0;
    bf16 zb = __float2bfloat16(0.f);
#pragma unroll
    for (int j = 0; j < 32; j++) {
        int f = tid + j * 256;
        int d = f >> 6, t = f & 63;
        dst[(long long)d * 1024 + t] = (d < 96) ? tile[t][d] : zb;
    }
}

// ---------------------------------------------------------------------------
// concat + bf16 cast for gate input
// ---------------------------------------------------------------------------
__global__ void concat_cast(const float* __restrict__ gcn_out, const float* __restrict__ attn_out,
                            bf16* __restrict__ gi)
{
    int i = blockIdx.x * 256 + threadIdx.x;
    if (i >= ROWS * DH) return;
    int r = i / DH, d = i - r * DH;
    gi[(long long)r * 1536 + d] = __float2bfloat16(gcn_out[i]);
    gi[(long long)r * 1536 + 768 + d] = __float2bfloat16(attn_out[i]);
}

// ---------------------------------------------------------------------------
// gate sigmoid + fuse + residual + LayerNorm; writes h (fp32) and hb (bf16)
// ---------------------------------------------------------------------------
__global__ __launch_bounds__(256)
void fuse_ln(const float* __restrict__ gate_lin, const float* __restrict__ gcn_out,
             const float* __restrict__ attn_out, float* __restrict__ h, bf16* __restrict__ hb,
             const float* __restrict__ lns, const float* __restrict__ lnb)
{
    int row = blockIdx.x;
    long long base = (long long)row * DH;
    int tid = threadIdx.x;
    __shared__ float red[4];
    float xv[3];
#pragma unroll
    for (int j = 0; j < 3; j++) {
        int d = tid + j * 256;
        float gl = gate_lin[base + d];
        float gv = 1.f / (1.f + __expf(-gl));
        float f = gv * gcn_out[base + d] + (1.f - gv) * attn_out[base + d];
        xv[j] = f + h[base + d];
    }
    float s = xv[0] + xv[1] + xv[2];
    for (int o = 32; o; o >>= 1) s += __shfl_xor(s, o);
    if ((tid & 63) == 0) red[tid >> 6] = s;
    __syncthreads();
    float mu = (red[0] + red[1] + red[2] + red[3]) * (1.f / 768.f);
    __syncthreads();
    float vs = 0.f;
#pragma unroll
    for (int j = 0; j < 3; j++) { float c = xv[j] - mu; vs += c * c; }
    for (int o = 32; o; o >>= 1) vs += __shfl_xor(vs, o);
    if ((tid & 63) == 0) red[tid >> 6] = vs;
    __syncthreads();
    float var = (red[0] + red[1] + red[2] + red[3]) * (1.f / 768.f);
    float rs = 1.f / sqrtf(var + 1e-5f);
#pragma unroll
    for (int j = 0; j < 3; j++) {
        int d = tid + j * 256;
        float y = (xv[j] - mu) * rs * lns[d] + lnb[d];
        h[base + d] = y;
        hb[base + d] = __float2bfloat16(y);
    }
}

// ---------------------------------------------------------------------------
// host-side GEMM wrapper
// ---------------------------------------------------------------------------
static void gemm(hipStream_t st, const bf16* A, const bf16* Bt, void* C, const float* bias,
                 int M, int N, int K, int lda, int ldb, int ldc,
                 long long aO, long long aI, long long bO, long long bI,
                 long long cO, long long cI, int zInner, int Z,
                 float scale, int storeBf16, int nMask)
{
    dim3 g(M / 128, (N + 127) / 128, Z);
    gemm_bf16_nt<<<g, dim3(256), 0, st>>>(A, Bt, C, bias, K, lda, ldb, ldc,
                                          aO, aI, bO, bI, cO, cI, zInner,
                                          scale, storeBf16, nMask);
}

extern "C" void kernel_launch(void* const* d_in, const int* in_sizes, int n_in,
                              void* d_out, int out_size, void* d_ws, size_t ws_size,
                              hipStream_t stream)
{
    (void)in_sizes; (void)n_in; (void)out_size; (void)ws_size;
    const float* x      = (const float*)d_in[0];
    const float* gcn_w  = (const float*)d_in[1];
    const float* gcn_b  = (const float*)d_in[2];
    const float* ain_w  = (const float*)d_in[3];
    const float* ain_b  = (const float*)d_in[4];
    const float* aout_w = (const float*)d_in[5];
    const float* aout_b = (const float*)d_in[6];
    const float* gate_w = (const float*)d_in[7];
    const float* gate_b = (const float*)d_in[8];
    const float* ln_s   = (const float*)d_in[9];
    const float* ln_b   = (const float*)d_in[10];
    const float* proj_w = (const float*)d_in[11];
    const float* proj_b = (const float*)d_in[12];
    float* out = (float*)d_out;

    // --- workspace layout (~216 MB; aliasing verified per-phase liveness) ---
    char* p = (char*)d_ws;
    auto alloc = [&](size_t bytes) {
        char* r = p;
        p += (bytes + 255) & ~(size_t)255;
        return r;
    };
    bf16* gcn_wt  = (bf16*)alloc((size_t)3 * 768 * 768 * 2);
    bf16* ain_wt  = (bf16*)alloc((size_t)3 * 2304 * 768 * 2);
    bf16* aout_wt = (bf16*)alloc((size_t)3 * 768 * 768 * 2);
    bf16* gate_wt = (bf16*)alloc((size_t)3 * 768 * 1536 * 2);
    bf16* proj_wt = (bf16*)alloc((size_t)768 * 768 * 2);
    bf16* hb      = (bf16*)alloc((size_t)ROWS * DH * 2);
    float* h      = (float*)alloc((size_t)ROWS * DH * 4);
    // qkvb region (37.7MB) also hosts gateinb [ROWS][1536] bf16 (dead-QKV phase)
    bf16* qkvb    = (bf16*)alloc((size_t)ROWS * 2304 * 2);
    bf16* gateinb = qkvb;
    // sim region (33.5MB fp32) also hosts attn_o [ROWS][DH] fp32
    float* sim    = (float*)alloc((size_t)ROWS * 1024 * 4);
    float* attn_o = sim;
    unsigned long long* mask = (unsigned long long*)alloc((size_t)ROWS * 16 * 8);
    float* dinv   = (float*)alloc((size_t)ROWS * 4);
    // g region (25.2MB) also hosts gate_l (g dead after spmm)
    float* g      = (float*)alloc((size_t)ROWS * DH * 4);
    float* gate_l = g;
    float* gcn_o  = (float*)alloc((size_t)ROWS * DH * 4);
    bf16* Vt      = (bf16*)alloc((size_t)64 * 128 * 1024 * 2);
    bf16* ob      = (bf16*)alloc((size_t)ROWS * DH * 2);
    // xc [ROWS][3072] bf16 (50.33MB) aliases g+gcn_o exactly
    bf16* xc      = (bf16*)g;

    // --- weights -> bf16, transposed [N][K] ---
    transpose_cast<<<dim3(24, 24, 3), 256, 0, stream>>>(gcn_w, gcn_wt, 768, 768);
    transpose_cast<<<dim3(24, 72, 3), 256, 0, stream>>>(ain_w, ain_wt, 768, 2304);
    transpose_cast<<<dim3(24, 24, 3), 256, 0, stream>>>(aout_w, aout_wt, 768, 768);
    transpose_cast<<<dim3(48, 24, 3), 256, 0, stream>>>(gate_w, gate_wt, 1536, 768);
    transpose_cast<<<dim3(24, 24, 1), 256, 0, stream>>>(proj_w, proj_wt, 768, 768);

    // --- x prep ---
    prep_x<<<cdiv(ROWS * DH, 256), 256, 0, stream>>>(x, h, hb, xc);

    // --- sim = x x^T with cross terms, per batch z ---
    gemm(stream, xc, xc + 768, sim, nullptr, 1024, 1024, 2304, 3072, 3072, 1024,
         (long long)1024 * 3072, 0, (long long)1024 * 3072, 0,
         (long long)1024 * 1024, 0, 1, 8, 1.f, 0, 1024);

    // --- adjacency: fused approx top-8 + exact fp64 rerank -> mask -> dinv ---
    zero_u64<<<cdiv(ROWS * 16, 256), 256, 0, stream>>>(mask, ROWS * 16);
    topk_rerank<<<ROWS, 256, 0, stream>>>(sim, x, mask);
    calc_dinv<<<cdiv(ROWS, 256), 256, 0, stream>>>(mask, dinv, ROWS);

    float sscale = 1.0f / sqrtf(96.0f);

    for (int l = 0; l < 3; l++) {
        // g = h @ gcn_w[l]   (fp32 out, bias added in spmm)
        gemm(stream, hb, gcn_wt + (long long)l * 768 * 768, g, nullptr,
             ROWS, 768, 768, 768, 768, 768, 0, 0, 0, 0, 0, 0, 1, 1, 1.f, 0, 768);
        // gcn_out = A_norm @ g + b
        spmm<<<dim3(1024, 8), 256, 0, stream>>>(mask, dinv, g, gcn_b + l * 768, gcn_o);
        // qkv = h @ w_in + b  (bf16 out)
        gemm(stream, hb, ain_wt + (long long)l * 2304 * 768, qkvb, ain_b + l * 2304,
             ROWS, 2304, 768, 768, 768, 2304, 0, 0, 0, 0, 0, 0, 1, 1, 1.f, 1, 2304);
        // V^T per (b,h), padded to 128 rows
        vt_transpose<<<dim3(16, 64), 256, 0, stream>>>(qkvb, Vt);
        // fused flash attention: one dispatch for all batches/heads
        flash_attn<<<dim3(8, 64), 256, 0, stream>>>(qkvb, Vt, ob, sscale);
        // attn_out = o @ w_out + b  (fp32)
        gemm(stream, ob, aout_wt + (long long)l * 768 * 768, attn_o, aout_b + l * 768,
             ROWS, 768, 768, 768, 768, 768, 0, 0, 0, 0, 0, 0, 1, 1, 1.f, 0, 768);
        // gate input concat (bf16)          [writes into dead-QKV region]
        concat_cast<<<cdiv(ROWS * DH, 256), 256, 0, stream>>>(gcn_o, attn_o, gateinb);
        // gate_lin = concat @ gate_w + b  (fp32)  [writes into dead-g region]
        gemm(stream, gateinb, gate_wt + (long long)l * 768 * 1536, gate_l, gate_b + l * 768,
             ROWS, 768, 1536, 1536, 1536, 768, 0, 0, 0, 0, 0, 0, 1, 1, 1.f, 0, 768);
        // sigmoid gate + fuse + residual + LN -> h, hb
        fuse_ln<<<ROWS, 256, 0, stream>>>(gate_l, gcn_o, attn_o, h, hb,
                                          ln_s + l * 768, ln_b + l * 768);
    }

    // out = h @ proj_w + proj_b (fp32)
    gemm(stream, hb, proj_wt, out, proj_b,
         ROWS, 768, 768, 768, 768, 768, 0, 0, 0, 0, 0, 0, 1, 1, 1.f, 0, 768);
}

// Round 9
// 1011.731 us; speedup vs baseline: 1.6796x; 1.1529x over previous
//
#include <hip/hip_runtime.h>
#include <hip/hip_bf16.h>
#include <math.h>

using bf16 = __hip_bfloat16;
typedef short s16x8 __attribute__((ext_vector_type(8)));
typedef float f32x4 __attribute__((ext_vector_type(4)));

#define ROWS 8192   // B*S
#define DH 768

static inline int cdiv(int a, int b) { return (a + b - 1) / b; }

// async global->LDS, 16B per lane; LDS dest must be wave-uniform base + lane*16
__device__ __forceinline__ void gld16(const bf16* g, bf16* l)
{
    __builtin_amdgcn_global_load_lds(
        (const __attribute__((address_space(1))) void*)g,
        (__attribute__((address_space(3))) void*)l, 16, 0, 0);
}

// ---------------------------------------------------------------------------
// Generic bf16 GEMM: C[M,N] = scale * (A[M,K] @ Bt[N,K]^T) + bias[N] (col<biasN)
// Double-buffered LDS + global_load_lds prefetch, ONE barrier per K-iter.
// L2 swizzle: supertiles of 8 M-blocks x all N-panels.
// ---------------------------------------------------------------------------
__global__ __launch_bounds__(256)
void gemm_bf16_nt(const bf16* __restrict__ A, const bf16* __restrict__ Bt,
                  void* __restrict__ Cout, const float* __restrict__ bias,
                  int K, int lda, int ldb, int ldc,
                  long long aO, long long aI, long long bO, long long bI,
                  long long cO, long long cI, int zInner,
                  float scale, int storeBf16, int nMask, int biasN)
{
    int z = blockIdx.z;
    int zo = z / zInner, zi = z - zo * zInner;
    const bf16* Ab = A + (long long)zo * aO + (long long)zi * aI;
    const bf16* Bb = Bt + (long long)zo * bO + (long long)zi * bI;
    long long cOff = (long long)zo * cO + (long long)zi * cI;

    __shared__ bf16 As[2 * 128 * 32];
    __shared__ bf16 Bs[2 * 128 * 32];

    int tid = threadIdx.x;
    int lane = tid & 63;
    int wid = tid >> 6;
    int wm = wid >> 1, wn = wid & 1;

    // L2-locality swizzle (identity when gridDim.x % 8 != 0)
    int nx = gridDim.x, ny = gridDim.y;
    int bx, by;
    if ((nx & 7) == 0) {
        int lin = blockIdx.y * nx + blockIdx.x;
        int t = lin >> 3;
        bx = (lin & 7) + (t / ny) * 8;
        by = t - (t / ny) * ny;
    } else { bx = blockIdx.x; by = blockIdx.y; }
    int m0 = bx * 128;
    int n0 = by * 128;

    f32x4 acc[4][4];
    f32x4 zero = {0.f, 0.f, 0.f, 0.f};
#pragma unroll
    for (int i = 0; i < 4; i++)
#pragma unroll
        for (int j = 0; j < 4; j++) acc[i][j] = zero;

    int f0 = tid, f1 = tid + 256;
    int r0 = f0 >> 2, c0 = (f0 & 3) * 8;
    int r1 = f1 >> 2, c1 = (f1 & 3) * 8;
    const bf16* a0p = Ab + (long long)(m0 + r0) * lda + c0;
    const bf16* a1p = Ab + (long long)(m0 + r1) * lda + c1;
    const bf16* b0p = Bb + (long long)(n0 + r0) * ldb + c0;
    const bf16* b1p = Bb + (long long)(n0 + r1) * ldb + c1;

    bf16* asw0 = As + wid * 512;
    bf16* asw1 = As + 2048 + wid * 512;
    bf16* bsw0 = Bs + wid * 512;
    bf16* bsw1 = Bs + 2048 + wid * 512;

    int mrow = lane & 15;
    int kcol = (lane >> 4) * 8;
    const bf16* aRead = As + (wm * 64 + mrow) * 32 + kcol;
    const bf16* bRead = Bs + (wn * 64 + mrow) * 32 + kcol;

    int nIter = K >> 5;
    gld16(a0p, asw0);
    gld16(a1p, asw1);
    gld16(b0p, bsw0);
    gld16(b1p, bsw1);

    for (int it = 0; it < nIter; it++) {
        __syncthreads();
        int cur = (it & 1) * 4096;
        int nxt = 4096 - cur;
        if (it + 1 < nIter) {
            int kn = (it + 1) << 5;
            gld16(a0p + kn, asw0 + nxt);
            gld16(a1p + kn, asw1 + nxt);
            gld16(b0p + kn, bsw0 + nxt);
            gld16(b1p + kn, bsw1 + nxt);
        }
        s16x8 af[4], bfr[4];
#pragma unroll
        for (int i = 0; i < 4; i++) af[i] = *(const s16x8*)(aRead + cur + i * 16 * 32);
#pragma unroll
        for (int i = 0; i < 4; i++) bfr[i] = *(const s16x8*)(bRead + cur + i * 16 * 32);
#pragma unroll
        for (int mi = 0; mi < 4; mi++)
#pragma unroll
            for (int ni = 0; ni < 4; ni++)
                acc[mi][ni] = __builtin_amdgcn_mfma_f32_16x16x32_bf16(
                    af[mi], bfr[ni], acc[mi][ni], 0, 0, 0);
    }

    int colL = lane & 15;
    int rq = (lane >> 4) * 4;
#pragma unroll
    for (int ni = 0; ni < 4; ni++) {
        int col = n0 + wn * 64 + ni * 16 + colL;
        if (col >= nMask) continue;
        float bv = (bias && col < biasN) ? bias[col] : 0.f;
#pragma unroll
        for (int mi = 0; mi < 4; mi++) {
#pragma unroll
            for (int r = 0; r < 4; r++) {
                int row = m0 + wm * 64 + mi * 16 + rq + r;
                float v = acc[mi][ni][r] * scale + bv;
                long long ci = cOff + (long long)row * ldc + col;
                if (storeBf16) ((bf16*)Cout)[ci] = __float2bfloat16(v);
                else           ((float*)Cout)[ci] = v;
            }
        }
    }
}

// ---------------------------------------------------------------------------
// Fused flash attention: S=QK^T (fp32), exp2-domain online softmax, O = P V.
// Grid (64 bh, 8 q-tiles) — all q-tiles of one bh share an XCD slot under
// round-robin so K re-reads hit L2. qg row stride 3072 (Q at +0, K at +768).
// cs = sscale*log2e pre-folded.
// ---------------------------------------------------------------------------
__global__ __launch_bounds__(256)
void flash_attn(const bf16* __restrict__ qg, const bf16* __restrict__ Vt,
                bf16* __restrict__ ob, float cs)
{
    int bh = blockIdx.x, qt = blockIdx.y;
    int b = bh >> 3, h = bh & 7;
    int q0 = qt * 128;

    __shared__ bf16 Ks[128 * 96];        // 24.6 KB
    __shared__ bf16 Ps[4 * 32 * 136];    // 34.8 KB, per-wave private (pad 136)

    int tid = threadIdx.x, lane = tid & 63, wid = tid >> 6;
    int quad = lane >> 4, m16 = lane & 15;

    // Q fragments in registers (A-operand: m=lane&15, k=quad*8+j)
    s16x8 qf[2][3];
#pragma unroll
    for (int s = 0; s < 2; s++) {
        int qrow = q0 + wid * 32 + s * 16 + m16;
        const bf16* qp = qg + (long long)(b * 1024 + qrow) * 3072 + h * 96 + quad * 8;
#pragma unroll
        for (int kk = 0; kk < 3; kk++)
            qf[s][kk] = *(const s16x8*)(qp + kk * 32);
    }

    f32x4 zero = {0.f, 0.f, 0.f, 0.f};
    f32x4 o_acc[2][6];
#pragma unroll
    for (int s = 0; s < 2; s++)
#pragma unroll
        for (int d = 0; d < 6; d++) o_acc[s][d] = zero;
    f32x4 m_run[2], l_run[2];
#pragma unroll
    for (int s = 0; s < 2; s++) {
        m_run[s] = {-3.0e38f, -3.0e38f, -3.0e38f, -3.0e38f};
        l_run[s] = zero;
    }

    bf16* Pw = Ps + wid * (32 * 136);
    const bf16* Kbase = qg + (long long)b * 1024 * 3072 + 768 + h * 96;
    const bf16* Vbase = Vt + (long long)bh * 128 * 1024;

    for (int kt = 0; kt < 8; kt++) {
        __syncthreads();                 // protect Ks from prior readers
#pragma unroll
        for (int i = 0; i < 6; i++) {
            int gby = i * 4096 + wid * 1024 + lane * 16;   // byte in tile
            int krow = gby / 192;
            int kcol = (gby - krow * 192) >> 1;
            gld16(Kbase + (long long)(kt * 128 + krow) * 3072 + kcol,
                  Ks + i * 2048 + wid * 512);
        }
        __syncthreads();                 // staging complete (vmcnt drain)

        // S = Q K^T, fp32 acc
        f32x4 sacc[2][8];
#pragma unroll
        for (int s = 0; s < 2; s++)
#pragma unroll
            for (int j = 0; j < 8; j++) sacc[s][j] = zero;
#pragma unroll
        for (int j = 0; j < 8; j++) {
            s16x8 kf[3];
#pragma unroll
            for (int kk = 0; kk < 3; kk++)
                kf[kk] = *(const s16x8*)(Ks + (j * 16 + m16) * 96 + kk * 32 + quad * 8);
#pragma unroll
            for (int s = 0; s < 2; s++)
#pragma unroll
                for (int kk = 0; kk < 3; kk++)
                    sacc[s][j] = __builtin_amdgcn_mfma_f32_16x16x32_bf16(
                        qf[s][kk], kf[kk], sacc[s][j], 0, 0, 0);
        }

        // exp2-domain online softmax per stripe; P -> bf16 -> per-wave LDS
#pragma unroll
        for (int s = 0; s < 2; s++) {
#pragma unroll
            for (int j = 0; j < 8; j++)
#pragma unroll
                for (int c = 0; c < 4; c++) sacc[s][j][c] *= cs;
            f32x4 tmax = sacc[s][0];
#pragma unroll
            for (int j = 1; j < 8; j++)
#pragma unroll
                for (int c = 0; c < 4; c++) tmax[c] = fmaxf(tmax[c], sacc[s][j][c]);
#pragma unroll
            for (int o = 1; o < 16; o <<= 1)
#pragma unroll
                for (int c = 0; c < 4; c++)
                    tmax[c] = fmaxf(tmax[c], __shfl_xor(tmax[c], o));
            f32x4 mnew, alpha;
#pragma unroll
            for (int c = 0; c < 4; c++) {
                mnew[c] = fmaxf(m_run[s][c], tmax[c]);
                alpha[c] = exp2f(m_run[s][c] - mnew[c]);
            }
            f32x4 tsum = zero;
#pragma unroll
            for (int j = 0; j < 8; j++) {
#pragma unroll
                for (int c = 0; c < 4; c++) {
                    float pv = exp2f(sacc[s][j][c] - mnew[c]);
                    tsum[c] += pv;
                    Pw[(s * 16 + quad * 4 + c) * 136 + j * 16 + m16] = __float2bfloat16(pv);
                }
            }
#pragma unroll
            for (int o = 1; o < 16; o <<= 1)
#pragma unroll
                for (int c = 0; c < 4; c++) tsum[c] += __shfl_xor(tsum[c], o);
#pragma unroll
            for (int c = 0; c < 4; c++)
                l_run[s][c] = l_run[s][c] * alpha[c] + tsum[c];
            m_run[s] = mnew;
#pragma unroll
            for (int d = 0; d < 6; d++)
#pragma unroll
                for (int c = 0; c < 4; c++) o_acc[s][d][c] *= alpha[c];
        }

        // P A-frags from per-wave LDS (no barrier: wave-private region)
        s16x8 pf[2][4];
#pragma unroll
        for (int s = 0; s < 2; s++)
#pragma unroll
            for (int kk = 0; kk < 4; kk++)
                pf[s][kk] = *(const s16x8*)(Pw + (s * 16 + m16) * 136 + kk * 32 + quad * 8);
        // O += P V  (V B-frags direct from Vt: n=d, k along t)
#pragma unroll
        for (int dt = 0; dt < 6; dt++) {
            s16x8 vf[4];
#pragma unroll
            for (int kk = 0; kk < 4; kk++)
                vf[kk] = *(const s16x8*)(Vbase + (long long)(dt * 16 + m16) * 1024
                                         + kt * 128 + kk * 32 + quad * 8);
#pragma unroll
            for (int s = 0; s < 2; s++)
#pragma unroll
                for (int kk = 0; kk < 4; kk++)
                    o_acc[s][dt] = __builtin_amdgcn_mfma_f32_16x16x32_bf16(
                        pf[s][kk], vf[kk], o_acc[s][dt], 0, 0, 0);
        }
    }

    // epilogue: O /= l, store bf16 into ob[row][h*96+d]
#pragma unroll
    for (int s = 0; s < 2; s++) {
        f32x4 inv;
#pragma unroll
        for (int c = 0; c < 4; c++) inv[c] = 1.f / l_run[s][c];
#pragma unroll
        for (int dt = 0; dt < 6; dt++) {
#pragma unroll
            for (int c = 0; c < 4; c++) {
                int row = q0 + wid * 32 + s * 16 + quad * 4 + c;
                int col = h * 96 + dt * 16 + m16;
                ob[(long long)(b * 1024 + row) * 768 + col] =
                    __float2bfloat16(o_acc[s][dt][c] * inv[c]);
            }
        }
    }
}

// ---------------------------------------------------------------------------
// Weight transpose+cast: in [z][K][N] fp32 (stride inZ) -> out [z][N][K] bf16
// (stride outZ)
// ---------------------------------------------------------------------------
__global__ __launch_bounds__(256)
void transpose_cast(const float* __restrict__ in, bf16* __restrict__ out,
                    int K, int N, long long inZ, long long outZ)
{
    long long izoff = (long long)blockIdx.z * inZ;
    long long ozoff = (long long)blockIdx.z * outZ;
    int k0 = blockIdx.x * 32, n0 = blockIdx.y * 32;
    __shared__ float t[32][33];
    int tx = threadIdx.x & 31, ty = threadIdx.x >> 5;  // ty: 0..7
#pragma unroll
    for (int j = 0; j < 32; j += 8)
        t[ty + j][tx] = in[izoff + (long long)(k0 + ty + j) * N + n0 + tx];
    __syncthreads();
#pragma unroll
    for (int j = 0; j < 32; j += 8)
        out[ozoff + (long long)(n0 + ty + j) * K + k0 + tx] = __float2bfloat16(t[tx][ty + j]);
}

// ---------------------------------------------------------------------------
// zero-fill u64 buffer (must run every call; harness poisons ws with 0xAA)
// ---------------------------------------------------------------------------
__global__ void zero_u64(unsigned long long* __restrict__ p, int n)
{
    int i = blockIdx.x * 256 + threadIdx.x;
    if (i < n) p[i] = 0ull;
}

// ---------------------------------------------------------------------------
// prep_x: h=x (fp32), hb=bf16(x)
// ---------------------------------------------------------------------------
__global__ __launch_bounds__(256)
void prep_x(const float* __restrict__ x, float* __restrict__ h,
            bf16* __restrict__ hb)
{
    int i = blockIdx.x * 256 + threadIdx.x;
    if (i >= ROWS * DH) return;
    float v = x[i];
    h[i] = v;
    hb[i] = __float2bfloat16(v);
}

// ---------------------------------------------------------------------------
// Fused top-k: register-resident wave-local top-8, wave-0 merge, exact fp64
// rerank -> top-5 -> symmetric adjacency bits (+ self loop). sim is bf16-level
// approx (err sigma ~0.08) but gap(5th,9th)~7 => true top-5 always in top-8;
// fp64 rerank restores exactness.
// ---------------------------------------------------------------------------
__global__ __launch_bounds__(256)
void topk_rerank(const float* __restrict__ sim, const float* __restrict__ x,
                 unsigned long long* __restrict__ mask)
{
    int row = blockIdx.x;            // b*1024 + s
    int b = row >> 10, s = row & 1023;
    int tid = threadIdx.x;
    int wid = tid >> 6, lane = tid & 63;

    __shared__ float wvals[4][8];
    __shared__ int   widx[4][8];
    __shared__ int   cand[8];
    __shared__ double val[8];

    int base = wid * 256 + lane * 4;
    float4 vv = *(const float4*)(sim + (long long)row * 1024 + base);
    float v0 = vv.x, v1 = vv.y, v2 = vv.z, v3 = vv.w;

    for (int r = 0; r < 8; r++) {
        float bv = v0; int bi = base;
        if (v1 > bv) { bv = v1; bi = base + 1; }
        if (v2 > bv) { bv = v2; bi = base + 2; }
        if (v3 > bv) { bv = v3; bi = base + 3; }
#pragma unroll
        for (int o = 1; o < 64; o <<= 1) {
            float ov = __shfl_xor(bv, o);
            int   oi = __shfl_xor(bi, o);
            if (ov > bv || (ov == bv && oi < bi)) { bv = ov; bi = oi; }
        }
        if ((bi >> 2) == (wid * 64 + lane)) {
            int sl = bi & 3;
            if (sl == 0) v0 = -3.4e38f;
            else if (sl == 1) v1 = -3.4e38f;
            else if (sl == 2) v2 = -3.4e38f;
            else v3 = -3.4e38f;
        }
        if (lane == 0) { wvals[wid][r] = bv; widx[wid][r] = bi; }
    }
    __syncthreads();
    if (wid == 0) {
        float mv = -3.4e38f; int mi = 0x7fffffff;
        if (lane < 32) { mv = wvals[lane >> 3][lane & 7]; mi = widx[lane >> 3][lane & 7]; }
        for (int r = 0; r < 8; r++) {
            float bv = mv; int bi = mi;
#pragma unroll
            for (int o = 1; o < 32; o <<= 1) {
                float ov = __shfl_xor(bv, o, 32);
                int   oi = __shfl_xor(bi, o, 32);
                if (ov > bv || (ov == bv && oi < bi)) { bv = ov; bi = oi; }
            }
            if (lane < 32 && bi == mi) mv = -3.4e38f;
            if (lane == 0) cand[r] = bi;
        }
    }
    __syncthreads();
    int g = tid >> 5, t = tid & 31;
    int c = cand[g];
    const float4* xs4 = (const float4*)(x + (long long)row * DH);
    const float4* xc4 = (const float4*)(x + ((long long)b * 1024 + c) * DH);
    double acc = 0.0;
#pragma unroll
    for (int j = 0; j < 6; j++) {
        float4 a = xs4[t + j * 32];
        float4 q = xc4[t + j * 32];
        acc += (double)a.x * q.x + (double)a.y * q.y
             + (double)a.z * q.z + (double)a.w * q.w;
    }
#pragma unroll
    for (int o = 16; o; o >>= 1) acc += __shfl_xor(acc, o, 32);
    if (t == 0) val[g] = acc;
    __syncthreads();
    if (tid == 0) {
        bool used[8] = {false, false, false, false, false, false, false, false};
        for (int r = 0; r < 5; r++) {
            int best = -1;
            for (int j = 0; j < 8; j++) {
                if (used[j]) continue;
                if (best < 0 || val[j] > val[best] ||
                    (val[j] == val[best] && cand[j] < cand[best])) best = j;
            }
            used[best] = true;
            int ci = cand[best];
            atomicOr(&mask[((long long)b * 1024 + s) * 16 + (ci >> 6)], 1ull << (ci & 63));
            atomicOr(&mask[((long long)b * 1024 + ci) * 16 + (s >> 6)], 1ull << (s & 63));
        }
        atomicOr(&mask[(long long)row * 16 + (s >> 6)], 1ull << (s & 63));
    }
}

__global__ void calc_dinv(const unsigned long long* __restrict__ mask,
                          float* __restrict__ dinv, int n)
{
    int i = blockIdx.x * 256 + threadIdx.x;
    if (i >= n) return;
    int c = 0;
#pragma unroll
    for (int w = 0; w < 16; w++) c += __popcll(mask[(long long)i * 16 + w]);
    dinv[i] = 1.f / sqrtf((float)c);
}

// ---------------------------------------------------------------------------
// SpMM: gate-in[b,s,0:768] = bf16( sum_t dinv[s]dinv[t] g[b,t,:] + gcn_b )
// g read as bf16 from qg cols 2304..3071 (row stride 3072)
// ---------------------------------------------------------------------------
__global__ __launch_bounds__(256)
void spmm(const unsigned long long* __restrict__ mask, const float* __restrict__ dinv,
          const bf16* __restrict__ qg, const float* __restrict__ bias,
          bf16* __restrict__ gout)
{
    int s = blockIdx.x, b = blockIdx.y;
    int row = b * 1024 + s;
    __shared__ unsigned long long mrow[16];
    int tid = threadIdx.x;
    if (tid < 16) mrow[tid] = mask[(long long)row * 16 + tid];
    __syncthreads();
    float ds = dinv[row];
    float a0 = 0.f, a1 = 0.f, a2 = 0.f;
    const bf16* gb = qg + (long long)b * 1024 * 3072 + 2304;
    const float* db = dinv + b * 1024;
    for (int w = 0; w < 16; w++) {
        unsigned long long bits = mrow[w];
        while (bits) {
            int t = (w << 6) + __ffsll(bits) - 1;
            bits &= bits - 1;
            float c = ds * db[t];
            const bf16* gr = gb + (long long)t * 3072;
            a0 += c * __bfloat162float(gr[tid]);
            a1 += c * __bfloat162float(gr[tid + 256]);
            a2 += c * __bfloat162float(gr[tid + 512]);
        }
    }
    bf16* o = gout + (long long)row * 1536;
    o[tid]       = __float2bfloat16(a0 + bias[tid]);
    o[tid + 256] = __float2bfloat16(a1 + bias[tid + 256]);
    o[tid + 512] = __float2bfloat16(a2 + bias[tid + 512]);
}

// ---------------------------------------------------------------------------
// Vt transpose: qg V-part [b, t, 1536+h*96+d] (stride 3072) -> Vt[b,h,d,t],
// d padded to 128
// ---------------------------------------------------------------------------
__global__ __launch_bounds__(256)
void vt_transpose(const bf16* __restrict__ qg, bf16* __restrict__ Vt)
{
    int bh = blockIdx.y;
    int b = bh >> 3, h = bh & 7;
    int t0 = blockIdx.x * 64;
    __shared__ bf16 tile[64][100];
    int tid = threadIdx.x;
    {
        int t = tid >> 2, c0 = (tid & 3) * 24;
        const bf16* src = qg + ((long long)(b * 1024 + t0 + t)) * 3072 + 1536 + h * 96 + c0;
#pragma unroll
        for (int j = 0; j < 24; j++) tile[t][c0 + j] = src[j];
    }
    __syncthreads();
    bf16* dst = Vt + ((long long)bh * 128) * 1024 + t0;
    bf16 zb = __float2bfloat16(0.f);
#pragma unroll
    for (int j = 0; j < 32; j++) {
        int f = tid + j * 256;
        int d = f >> 6, t = f & 63;
        dst[(long long)d * 1024 + t] = (d < 96) ? tile[t][d] : zb;
    }
}

// ---------------------------------------------------------------------------
// gate sigmoid + fuse + residual + LayerNorm; gcn/attn read bf16 from gi
// ---------------------------------------------------------------------------
__global__ __launch_bounds__(256)
void fuse_ln(const float* __restrict__ gate_lin, const bf16* __restrict__ gi,
             float* __restrict__ h, bf16* __restrict__ hb,
             const float* __restrict__ lns, const float* __restrict__ lnb)
{
    int row = blockIdx.x;
    long long base = (long long)row * DH;
    long long gbase = (long long)row * 1536;
    int tid = threadIdx.x;
    __shared__ float red[4];
    float xv[3];
#pragma unroll
    for (int j = 0; j < 3; j++) {
        int d = tid + j * 256;
        float gl = gate_lin[base + d];
        float gv = 1.f / (1.f + __expf(-gl));
        float gcn = __bfloat162float(gi[gbase + d]);
        float attn = __bfloat162float(gi[gbase + 768 + d]);
        float f = gv * gcn + (1.f - gv) * attn;
        xv[j] = f + h[base + d];
    }
    float s = xv[0] + xv[1] + xv[2];
    for (int o = 32; o; o >>= 1) s += __shfl_xor(s, o);
    if ((tid & 63) == 0) red[tid >> 6] = s;
    __syncthreads();
    float mu = (red[0] + red[1] + red[2] + red[3]) * (1.f / 768.f);
    __syncthreads();
    float vs = 0.f;
#pragma unroll
    for (int j = 0; j < 3; j++) { float c = xv[j] - mu; vs += c * c; }
    for (int o = 32; o; o >>= 1) vs += __shfl_xor(vs, o);
    if ((tid & 63) == 0) red[tid >> 6] = vs;
    __syncthreads();
    float var = (red[0] + red[1] + red[2] + red[3]) * (1.f / 768.f);
    float rs = 1.f / sqrtf(var + 1e-5f);
#pragma unroll
    for (int j = 0; j < 3; j++) {
        int d = tid + j * 256;
        float y = (xv[j] - mu) * rs * lns[d] + lnb[d];
        h[base + d] = y;
        hb[base + d] = __float2bfloat16(y);
    }
}

// ---------------------------------------------------------------------------
// host-side GEMM wrapper
// ---------------------------------------------------------------------------
static void gemm(hipStream_t st, const bf16* A, const bf16* Bt, void* C, const float* bias,
                 int M, int N, int K, int lda, int ldb, int ldc,
                 long long aO, long long aI, long long bO, long long bI,
                 long long cO, long long cI, int zInner, int Z,
                 float scale, int storeBf16, int nMask, int biasN)
{
    dim3 g(M / 128, (N + 127) / 128, Z);
    gemm_bf16_nt<<<g, dim3(256), 0, st>>>(A, Bt, C, bias, K, lda, ldb, ldc,
                                          aO, aI, bO, bI, cO, cI, zInner,
                                          scale, storeBf16, nMask, biasN);
}

extern "C" void kernel_launch(void* const* d_in, const int* in_sizes, int n_in,
                              void* d_out, int out_size, void* d_ws, size_t ws_size,
                              hipStream_t stream)
{
    (void)in_sizes; (void)n_in; (void)out_size; (void)ws_size;
    const float* x      = (const float*)d_in[0];
    const float* gcn_w  = (const float*)d_in[1];
    const float* gcn_b  = (const float*)d_in[2];
    const float* ain_w  = (const float*)d_in[3];
    const float* ain_b  = (const float*)d_in[4];
    const float* aout_w = (const float*)d_in[5];
    const float* aout_b = (const float*)d_in[6];
    const float* gate_w = (const float*)d_in[7];
    const float* gate_b = (const float*)d_in[8];
    const float* ln_s   = (const float*)d_in[9];
    const float* ln_b   = (const float*)d_in[10];
    const float* proj_w = (const float*)d_in[11];
    const float* proj_b = (const float*)d_in[12];
    float* out = (float*)d_out;

    // --- workspace layout (~212 MiB) ---
    char* p = (char*)d_ws;
    auto alloc = [&](size_t bytes) {
        char* r = p;
        p += (bytes + 255) & ~(size_t)255;
        return r;
    };
    // combined [w_in | gcn_w]^T per layer: [3][3072][768] bf16
    bf16* qgw     = (bf16*)alloc((size_t)3 * 3072 * 768 * 2);
    bf16* aout_wt = (bf16*)alloc((size_t)3 * 768 * 768 * 2);
    bf16* gate_wt = (bf16*)alloc((size_t)3 * 768 * 1536 * 2);
    bf16* proj_wt = (bf16*)alloc((size_t)768 * 768 * 2);
    bf16* hb      = (bf16*)alloc((size_t)ROWS * DH * 2);
    float* h      = (float*)alloc((size_t)ROWS * DH * 4);
    bf16* qg      = (bf16*)alloc((size_t)ROWS * 3072 * 2);   // [qkv | g]
    // sim (33.5MB fp32, dead after topk) hosts Vt (16.8MB) in the layer loop
    float* sim    = (float*)alloc((size_t)ROWS * 1024 * 4);
    bf16* Vt      = (bf16*)sim;
    unsigned long long* mask = (unsigned long long*)alloc((size_t)ROWS * 16 * 8);
    float* dinv   = (float*)alloc((size_t)ROWS * 4);
    float* gate_l = (float*)alloc((size_t)ROWS * DH * 4);
    bf16* gateinb = (bf16*)alloc((size_t)ROWS * 1536 * 2);
    bf16* ob      = (bf16*)alloc((size_t)ROWS * DH * 2);

    // --- weights -> bf16, transposed [N][K] ---
    transpose_cast<<<dim3(24, 72, 3), 256, 0, stream>>>(
        ain_w, qgw, 768, 2304, (long long)768 * 2304, (long long)3072 * 768);
    transpose_cast<<<dim3(24, 24, 3), 256, 0, stream>>>(
        gcn_w, qgw + (long long)2304 * 768, 768, 768,
        (long long)768 * 768, (long long)3072 * 768);
    transpose_cast<<<dim3(24, 24, 3), 256, 0, stream>>>(
        aout_w, aout_wt, 768, 768, (long long)768 * 768, (long long)768 * 768);
    transpose_cast<<<dim3(48, 24, 3), 256, 0, stream>>>(
        gate_w, gate_wt, 1536, 768, (long long)1536 * 768, (long long)768 * 1536);
    transpose_cast<<<dim3(24, 24, 1), 256, 0, stream>>>(
        proj_w, proj_wt, 768, 768, 0, 0);

    // --- x prep ---
    prep_x<<<cdiv(ROWS * DH, 256), 256, 0, stream>>>(x, h, hb);

    // --- sim = hb hb^T per batch (bf16 approx; rerank below is exact) ---
    gemm(stream, hb, hb, sim, nullptr, 1024, 1024, 768, 768, 768, 1024,
         (long long)1024 * 768, 0, (long long)1024 * 768, 0,
         (long long)1024 * 1024, 0, 1, 8, 1.f, 0, 1024, 0);

    // --- adjacency: approx top-8 + exact fp64 rerank -> mask -> dinv ---
    zero_u64<<<cdiv(ROWS * 16, 256), 256, 0, stream>>>(mask, ROWS * 16);
    topk_rerank<<<ROWS, 256, 0, stream>>>(sim, x, mask);
    calc_dinv<<<cdiv(ROWS, 256), 256, 0, stream>>>(mask, dinv, ROWS);

    float cs = 1.4426950408889634f / sqrtf(96.0f);

    for (int l = 0; l < 3; l++) {
        // qg = h @ [w_in | gcn_w] + [ain_b | 0]  (bf16 out, N=3072)
        gemm(stream, hb, qgw + (long long)l * 3072 * 768, qg, ain_b + l * 2304,
             ROWS, 3072, 768, 768, 768, 3072, 0, 0, 0, 0, 0, 0, 1, 1,
             1.f, 1, 3072, 2304);
        // gate-in[:,0:768] = bf16(A_norm @ g + gcn_b)
        spmm<<<dim3(1024, 8), 256, 0, stream>>>(mask, dinv, qg, gcn_b + l * 768, gateinb);
        // V^T per (b,h), padded to 128 rows
        vt_transpose<<<dim3(16, 64), 256, 0, stream>>>(qg, Vt);
        // fused flash attention: one dispatch for all batches/heads
        flash_attn<<<dim3(64, 8), 256, 0, stream>>>(qg, Vt, ob, cs);
        // gate-in[:,768:1536] = bf16(ob @ w_out + aout_b)
        gemm(stream, ob, aout_wt + (long long)l * 768 * 768,
             (void*)(gateinb + 768), aout_b + l * 768,
             ROWS, 768, 768, 768, 768, 1536, 0, 0, 0, 0, 0, 0, 1, 1,
             1.f, 1, 768, 768);
        // gate_lin = gate-in @ gate_w + gate_b  (fp32)
        gemm(stream, gateinb, gate_wt + (long long)l * 768 * 1536, gate_l,
             gate_b + l * 768, ROWS, 768, 1536, 1536, 1536, 768,
             0, 0, 0, 0, 0, 0, 1, 1, 1.f, 0, 768, 768);
        // sigmoid gate + fuse + residual + LN -> h, hb
        fuse_ln<<<ROWS, 256, 0, stream>>>(gate_l, gateinb, h, hb,
                                          ln_s + l * 768, ln_b + l * 768);
    }

    // out = h @ proj_w + proj_b (fp32)
    gemm(stream, hb, proj_wt, out, proj_b,
         ROWS, 768, 768, 768, 768, 768, 0, 0, 0, 0, 0, 0, 1, 1, 1.f, 0, 768, 768);
}